// Round 6
// baseline (720.359 us; speedup 1.0000x reference)
//
#include <hip/hip_runtime.h>

// 3x3 conv (sparse weights treated dense), NCHW/OIHW, stride1 pad1, fp32 I/O.
// B=32, CIN=COUT=256, H=W=56.
//
// R6: same per-wave shape as R5 (64 cout x 112 pix, acc[4][7]) but 8 waves
// per block: 256 cout x 224 pix (4 output rows), grid 448. LDS = 2 x 32KB
// (6 input rows x 58 slots, padded to 2048 chunks) -> 2 blocks/CU =
// 16 waves/CU = 4 waves/SIMD (2x R5's TLP). R5 was latency-bound:
// MfmaUtil 30 / VALU 10 / LDS ~22% with 2 waves/SIMD.

typedef __attribute__((ext_vector_type(8))) short short8;
typedef __attribute__((ext_vector_type(4))) float f32x4;
typedef __attribute__((ext_vector_type(4))) int i32x4;

constexpr int BB = 32, CIN = 256, COUT = 256, H = 56, W = 56, HW = H * W;
constexpr int HP = 58, WP = 58;

constexpr size_t XP_ELEMS = (size_t)BB * HP * WP * CIN;
constexpr size_t WB_ELEMS = (size_t)COUT * 9 * CIN;
constexpr size_t WS_NEEDED = (XP_ELEMS + WB_ELEMS) * 2;

__device__ __forceinline__ ushort f2bf(float f) {
    unsigned x = __float_as_uint(f);
    unsigned r = (x + 0x7FFFu + ((x >> 16) & 1u)) >> 16;   // RNE
    return (ushort)r;
}

// ---------------- prep kernels (unchanged) ----------------

__global__ __launch_bounds__(256)
void prep_xp(const float* __restrict__ x, ushort* __restrict__ xp) {
    const int bi = blockIdx.x;            // b*58 + padded row i
    const int b = bi / HP, i = bi % HP;
    ushort* dst = xp + (size_t)bi * WP * CIN;
    const int tid = threadIdx.x;

    if (i == 0 || i == HP - 1) {
        i32x4 z = {0, 0, 0, 0};
        for (int k = tid; k < WP * CIN / 8; k += 256) ((i32x4*)dst)[k] = z;
        return;
    }

    __shared__ ushort t[W][CIN + 2];
    const int lane = tid & 63, wv = tid >> 6;
    if (lane < W) {
        const float* src = x + (size_t)b * CIN * HW + (size_t)(i - 1) * W + lane;
        for (int cin = wv; cin < CIN; cin += 4)
            t[lane][cin] = f2bf(src[(size_t)cin * HW]);
    }
    __syncthreads();
    for (int c = 0; c < WP; ++c)
        dst[c * CIN + tid] = (c == 0 || c == WP - 1) ? (ushort)0 : t[c - 1][tid];
}

__global__ __launch_bounds__(256)
void prep_wb(const float* __restrict__ w, ushort* __restrict__ wb) {
    const int d = blockIdx.x * 256 + threadIdx.x;  // (cout*9+tap)*256+cin
    const int cin = d & 255;
    const int rest = d >> 8;
    const int tap = rest % 9;
    const int cout = rest / 9;
    wb[d] = f2bf(w[((size_t)cout * CIN + cin) * 9 + tap]);
}

// ---------------- MFMA conv ----------------

#define SCHED_FENCE() __builtin_amdgcn_sched_barrier(0)

__device__ __forceinline__ void gload_lds16(const ushort* g, ushort* l) {
    __builtin_amdgcn_global_load_lds(
        (const __attribute__((address_space(1))) void*)g,
        (__attribute__((address_space(3))) void*)l, 16, 0, 0);
}

// xs: slot = r*58 + col (6 input rows x 58 cols = 348 slots), 5 chunks/slot
// (pieces 0..3 = 8 cins each, piece 4 = pad). 348*5 = 1740 chunks used,
// buffer padded to 2048 chunks (32KB) so out-of-range dummy chunks are safe.
constexpr int XCH = 2048;

__global__ __launch_bounds__(512, 4)
void conv_mfma(const ushort* __restrict__ xp, const ushort* __restrict__ wb,
               float* __restrict__ out) {
    // XCD-aware swizzle: 448 blocks = 8 * 56
    int bx = blockIdx.x;
    bx = (bx & 7) * 56 + (bx >> 3);

    const int b  = bx / 14;
    const int h0 = (bx % 14) * 4;          // 4 output rows h0..h0+3

    const int tid  = threadIdx.x;
    const int wv   = tid >> 6;             // 0..7
    const int mv   = wv >> 1;              // couts [64mv, 64mv+64)
    const int nv   = wv & 1;               // pixel rows {h0+2nv, h0+2nv+1}
    const int lane = tid & 63;
    const int ml   = lane & 15;
    const int g    = lane >> 4;

    __shared__ ushort xs[2][XCH * 8];      // 2 x 32768 B

    // B-frag LDS elem offsets: pixel p = nf*16+ml in this wave's 112-pix strip
    int boff[7];
    #pragma unroll
    for (int nf = 0; nf < 7; ++nf) {
        const int p = nf * 16 + ml;
        const int hl = (p >= 56) ? 1 : 0;
        const int wl = p - 56 * hl;
        boff[nf] = ((2 * nv + hl) * 58 + wl) * 40 + 8 * g;
    }

    // gload src elem offsets (4 chunks per thread per cin-block)
    const size_t base_b = ((size_t)b * HP + h0) * WP * CIN;  // 6 rows contiguous
    int goff[4];
    #pragma unroll
    for (int k = 0; k < 4; ++k) {
        const int c = 512 * k + tid;
        const int s = c / 5, piece = c - s * 5;
        const bool ok = (c < 1740) && (piece < 4);
        goff[k] = ok ? (s * 256 + piece * 8) : 0;
    }

    // A-frag global base: wave mv covers couts {64mv+16fm+ml}, frag fm at +fm*36864
    const ushort* abase = wb + (size_t)((64 * mv + ml) * 9) * 256 + 8 * g;

    f32x4 acc[4][7] = {};

    // prologue: stage cb0 -> buf0 (dest = wave-uniform base; HW adds lane*16)
    #pragma unroll
    for (int k = 0; k < 4; ++k)
        gload_lds16(xp + base_b + goff[k], &xs[0][(512 * k + 64 * wv) * 8]);

    for (int cb = 0; cb < 8; ++cb) {
        const int cur = cb & 1;
        __builtin_amdgcn_s_barrier();      // B1: all waves done reading buf[cur^1]
        SCHED_FENCE();
        if (cb < 7) {
            #pragma unroll
            for (int k = 0; k < 4; ++k)
                gload_lds16(xp + base_b + goff[k] + (cb + 1) * 32,
                            &xs[cur ^ 1][(512 * k + 64 * wv) * 8]);
            SCHED_FENCE();
            asm volatile("s_waitcnt vmcnt(4)" ::: "memory");  // cb's 4 done, cb+1's fly
            SCHED_FENCE();
        } else {
            SCHED_FENCE();
            asm volatile("s_waitcnt vmcnt(0)" ::: "memory");
            SCHED_FENCE();
        }
        __builtin_amdgcn_s_barrier();      // B2: buf[cur] fully written
        SCHED_FENCE();

        const ushort* xbuf = &xs[cur][0];
        const ushort* ab = abase + cb * 32;
        #pragma unroll
        for (int tap = 0; tap < 9; ++tap) {
            const int kh = tap / 3, kw = tap - kh * 3;
            const int toff = (kh * 58 + kw) * 40;

            short8 a0 = *(const short8*)(ab + tap * 256);
            short8 a1 = *(const short8*)(ab + tap * 256 + 36864);
            short8 a2 = *(const short8*)(ab + tap * 256 + 2 * 36864);
            short8 a3 = *(const short8*)(ab + tap * 256 + 3 * 36864);
            #pragma unroll
            for (int nf = 0; nf < 7; ++nf) {
                const short8 bf = *(const short8*)(xbuf + boff[nf] + toff);
                acc[0][nf] = __builtin_amdgcn_mfma_f32_16x16x32_bf16(a0, bf, acc[0][nf], 0, 0, 0);
                acc[1][nf] = __builtin_amdgcn_mfma_f32_16x16x32_bf16(a1, bf, acc[1][nf], 0, 0, 0);
                acc[2][nf] = __builtin_amdgcn_mfma_f32_16x16x32_bf16(a2, bf, acc[2][nf], 0, 0, 0);
                acc[3][nf] = __builtin_amdgcn_mfma_f32_16x16x32_bf16(a3, bf, acc[3][nf], 0, 0, 0);
            }
        }
    }

    // epilogue: D[row=4g+r][col=ml] (verified R2-R5)
    float* ob = out + (size_t)b * COUT * HW + (size_t)(h0 + 2 * nv) * W;
    #pragma unroll
    for (int fm = 0; fm < 4; ++fm)
        #pragma unroll
        for (int nf = 0; nf < 7; ++nf)
            #pragma unroll
            for (int r = 0; r < 4; ++r) {
                const int cout_l = 64 * mv + 16 * fm + 4 * g + r;
                const int p = nf * 16 + ml;
                const int hh = (p >= 56) ? 1 : 0;
                const int ww = p - 56 * hh;
                ob[(size_t)cout_l * HW + hh * W + ww] = acc[fm][nf][r];
            }
}

// ---------------- R1 fallback (fp32 sparse direct) ----------------

constexpr int WSZ = CIN * 9;
constexpr int NIN = 54 * 54;

__global__ __launch_bounds__(256)
void sparse_conv3x3(const float* __restrict__ x,
                    const float* __restrict__ wgt,
                    float* __restrict__ out) {
    const int bc = blockIdx.x, cout = bc % COUT, b = bc / COUT;
    const int tid = threadIdx.x;
    __shared__ int2 s_ent[WSZ];
    __shared__ unsigned char s_kk[WSZ];
    __shared__ int s_cnt[257];
    const float* wc = wgt + (size_t)cout * WSZ;
    float mv[9]; int cnt = 0;
    #pragma unroll
    for (int i = 0; i < 9; ++i) { mv[i] = wc[tid * 9 + i]; if (mv[i] != 0.0f) cnt++; }
    s_cnt[tid] = cnt; __syncthreads();
    if (tid == 0) { int run = 0; for (int t = 0; t < 256; ++t) { int c = s_cnt[t]; s_cnt[t] = run; run += c; } s_cnt[256] = run; }
    __syncthreads();
    { int pos = s_cnt[tid];
      #pragma unroll
      for (int i = 0; i < 9; ++i) if (mv[i] != 0.0f) {
          const int kh = i / 3, kw = i - kh * 3;
          int2 e; e.x = (tid * HW + (kh - 1) * W + (kw - 1)) * 4; e.y = __float_as_int(mv[i]);
          s_ent[pos] = e; s_kk[pos] = (unsigned char)(kh | (kw << 4)); pos++; } }
    __syncthreads();
    const int nnz = s_cnt[256];
    const char* xb = (const char*)(x + (size_t)b * CIN * HW);
    float* ob = out + (size_t)bc * HW;
    for (int o = tid; o < HW; o += 256) {
        int h, w; bool interior = (o < NIN);
        if (interior) { h = 1 + o / 54; w = 1 + (o - (h - 1) * 54); }
        else { int o2 = o - NIN;
            if (o2 < 56) { h = 0; w = o2; } else if (o2 < 112) { h = 55; w = o2 - 56; }
            else if (o2 < 166) { h = 1 + (o2 - 112); w = 0; } else { h = 1 + (o2 - 166); w = 55; } }
        const char* pb = xb + (size_t)(h * W + w) * 4;
        float acc = 0.0f;
        if (interior) {
            #pragma unroll 4
            for (int e = 0; e < nnz; ++e) { const int2 en = s_ent[e];
                acc = fmaf(__int_as_float(en.y), *(const float*)(pb + en.x), acc); }
        } else {
            const int h1 = h - 1, w1 = w - 1;
            for (int e = 0; e < nnz; ++e) { const int2 en = s_ent[e]; const int kk = s_kk[e];
                const int hh = h1 + (kk & 15), ww = w1 + (kk >> 4);
                if ((unsigned)hh < (unsigned)H && (unsigned)ww < (unsigned)W)
                    acc = fmaf(__int_as_float(en.y), *(const float*)(pb + en.x), acc); } }
        ob[h * W + w] = acc;
    }
}

// ---------------- launch ----------------

extern "C" void kernel_launch(void* const* d_in, const int* in_sizes, int n_in,
                              void* d_out, int out_size, void* d_ws, size_t ws_size,
                              hipStream_t stream) {
    const float* x = (const float*)d_in[0];
    const float* w = (const float*)d_in[1];
    float* out = (float*)d_out;

    if (ws_size >= WS_NEEDED) {
        ushort* xp = (ushort*)d_ws;
        ushort* wbp = xp + XP_ELEMS;
        prep_xp<<<BB * HP, 256, 0, stream>>>(x, xp);
        prep_wb<<<(int)(WB_ELEMS / 256), 256, 0, stream>>>(w, wbp);
        conv_mfma<<<448, 512, 0, stream>>>(xp, wbp, out);
    } else {
        sparse_conv3x3<<<BB * COUT, 256, 0, stream>>>(x, w, out);
    }
}

// Round 7
// 303.412 us; speedup vs baseline: 2.3742x; 2.3742x over previous
//
#include <hip/hip_runtime.h>

// 3x3 conv (sparse weights treated dense), NCHW/OIHW, stride1 pad1, fp32 I/O.
// B=32, CIN=COUT=256, H=W=56.
//
// R7: mfma_f32_32x32x16_bf16, wave = 64 cout x 64 pix (M_rep2 x N_rep2,
// acc = 2x2x16 = 64 regs vs R5's 112 at the same A/B reuse ratios).
// Block = 4 waves all-M (256 cout x 64 pix). Goal: ~140-160 total regs ->
// 3 waves/SIMD (R5 was latency-bound at 2 waves/SIMD: MfmaUtil 30%).
// 64-pix strips tile each plane exactly (3136/64=49), span 2 output rows ->
// same 4-row x 58-slot LDS tile + gload_lds/vmcnt(5) staging as R5.
// Grid 1568 = 8*196 (XCD swizzle). (256,2) bound: no-spill guarantee;
// occupancy comes from actual reg usage.

typedef __attribute__((ext_vector_type(8))) short short8;
typedef __attribute__((ext_vector_type(4))) float f32x4;
typedef __attribute__((ext_vector_type(16))) float f32x16;
typedef __attribute__((ext_vector_type(4))) int i32x4;

constexpr int BB = 32, CIN = 256, COUT = 256, H = 56, W = 56, HW = H * W;
constexpr int HP = 58, WP = 58;

constexpr size_t XP_ELEMS = (size_t)BB * HP * WP * CIN;
constexpr size_t WB_ELEMS = (size_t)COUT * 9 * CIN;
constexpr size_t WS_NEEDED = (XP_ELEMS + WB_ELEMS) * 2;

__device__ __forceinline__ ushort f2bf(float f) {
    unsigned x = __float_as_uint(f);
    unsigned r = (x + 0x7FFFu + ((x >> 16) & 1u)) >> 16;   // RNE
    return (ushort)r;
}

// ---------------- prep kernels (unchanged) ----------------

__global__ __launch_bounds__(256)
void prep_xp(const float* __restrict__ x, ushort* __restrict__ xp) {
    const int bi = blockIdx.x;            // b*58 + padded row i
    const int b = bi / HP, i = bi % HP;
    ushort* dst = xp + (size_t)bi * WP * CIN;
    const int tid = threadIdx.x;

    if (i == 0 || i == HP - 1) {
        i32x4 z = {0, 0, 0, 0};
        for (int k = tid; k < WP * CIN / 8; k += 256) ((i32x4*)dst)[k] = z;
        return;
    }

    __shared__ ushort t[W][CIN + 2];
    const int lane = tid & 63, wv = tid >> 6;
    if (lane < W) {
        const float* src = x + (size_t)b * CIN * HW + (size_t)(i - 1) * W + lane;
        for (int cin = wv; cin < CIN; cin += 4)
            t[lane][cin] = f2bf(src[(size_t)cin * HW]);
    }
    __syncthreads();
    for (int c = 0; c < WP; ++c)
        dst[c * CIN + tid] = (c == 0 || c == WP - 1) ? (ushort)0 : t[c - 1][tid];
}

__global__ __launch_bounds__(256)
void prep_wb(const float* __restrict__ w, ushort* __restrict__ wb) {
    const int d = blockIdx.x * 256 + threadIdx.x;  // (cout*9+tap)*256+cin
    const int cin = d & 255;
    const int rest = d >> 8;
    const int tap = rest % 9;
    const int cout = rest / 9;
    wb[d] = f2bf(w[((size_t)cout * CIN + cin) * 9 + tap]);
}

// ---------------- MFMA conv ----------------

#define SCHED_FENCE() __builtin_amdgcn_sched_barrier(0)

__device__ __forceinline__ void gload_lds16(const ushort* g, ushort* l) {
    __builtin_amdgcn_global_load_lds(
        (const __attribute__((address_space(1))) void*)g,
        (__attribute__((address_space(3))) void*)l, 16, 0, 0);
}

// xs: slot = r*58 + col (4 input rows x 58 cols = 232 slots), 5 chunks/slot
// (pieces 0..3 = 8 cins each, piece 4 = pad). 1160 chunks used, pad to 1280.
constexpr int XCH = 1280;

__global__ __launch_bounds__(256, 2)
void conv_mfma(const ushort* __restrict__ xp, const ushort* __restrict__ wb,
               float* __restrict__ out) {
    // XCD-aware swizzle: 1568 blocks = 8 * 196
    int bx = blockIdx.x;
    bx = (bx & 7) * 196 + (bx >> 3);

    const int b  = bx / 49;
    const int t  = bx % 49;
    const int p0 = t * 64;                 // first pixel of the 64-pix strip
    const int r0 = p0 / 56;                // first (padded) input row to stage

    const int tid  = threadIdx.x;
    const int wv   = tid >> 6;             // wave -> couts [64wv, 64wv+64)
    const int lane = tid & 63;
    const int ml   = lane & 31;            // pixel / cout row within 32-group
    const int kg   = lane >> 5;            // k-half: k = 8*kg + j

    __shared__ ushort xs[2][XCH * 8];      // 2 x 20480 B

    // B-frag LDS elem offsets: pixel p_ = p0 + 32n + ml
    int boff[2];
    #pragma unroll
    for (int n = 0; n < 2; ++n) {
        const int p_  = p0 + 32 * n + ml;
        const int rr  = p_ / 56 - r0;      // 0 or 1
        const int col = p_ % 56;
        boff[n] = (rr * 58 + col) * 40 + kg * 8;
    }

    // gload src elem offsets (5 chunks per thread per cin-block)
    const size_t base_b = ((size_t)b * HP + r0) * WP * CIN;
    int goff[5];
    #pragma unroll
    for (int k = 0; k < 5; ++k) {
        const int c = 256 * k + tid;
        const int s = c / 5, piece = c - s * 5;
        const bool ok = (c < 1160) && (piece < 4);
        goff[k] = ok ? (s * 256 + piece * 8) : 0;     // slots contiguous in xp
    }

    // A-frag global base: m-frag covers couts 64wv+32m+ml; k = 8kg+j
    const ushort* abase = wb + (size_t)((64 * wv + ml) * 9) * 256 + kg * 8;
    constexpr int MSTR = 32 * 9 * 256;     // cout+32 stride in wb elems

    f32x16 acc[2][2] = {};

    // prologue: stage cb0 -> buf0 (dest = wave-uniform base; HW adds lane*16)
    #pragma unroll
    for (int k = 0; k < 5; ++k)
        gload_lds16(xp + base_b + goff[k], &xs[0][(256 * k + 64 * wv) * 8]);

    for (int cb = 0; cb < 8; ++cb) {
        const int cur = cb & 1;
        __builtin_amdgcn_s_barrier();      // B1: all waves done reading buf[cur^1]
        SCHED_FENCE();
        if (cb < 7) {
            #pragma unroll
            for (int k = 0; k < 5; ++k)
                gload_lds16(xp + base_b + goff[k] + (cb + 1) * 32,
                            &xs[cur ^ 1][(256 * k + 64 * wv) * 8]);
            SCHED_FENCE();
            asm volatile("s_waitcnt vmcnt(5)" ::: "memory");  // cb's 5 done, cb+1's fly
            SCHED_FENCE();
        } else {
            SCHED_FENCE();
            asm volatile("s_waitcnt vmcnt(0)" ::: "memory");
            SCHED_FENCE();
        }
        __builtin_amdgcn_s_barrier();      // B2: buf[cur] fully written
        SCHED_FENCE();

        const ushort* xbuf = &xs[cur][0];
        const ushort* ab = abase + cb * 32;
        #pragma unroll
        for (int tap = 0; tap < 9; ++tap) {
            const int kh = tap / 3, kw = tap - kh * 3;
            const int toff = (kh * 58 + kw) * 40;
            #pragma unroll
            for (int ks = 0; ks < 2; ++ks) {
                const short8 a0 = *(const short8*)(ab + tap * 256 + ks * 16);
                const short8 a1 = *(const short8*)(ab + tap * 256 + ks * 16 + MSTR);
                const short8 b0 = *(const short8*)(xbuf + boff[0] + toff + ks * 16);
                const short8 b1 = *(const short8*)(xbuf + boff[1] + toff + ks * 16);
                acc[0][0] = __builtin_amdgcn_mfma_f32_32x32x16_bf16(a0, b0, acc[0][0], 0, 0, 0);
                acc[0][1] = __builtin_amdgcn_mfma_f32_32x32x16_bf16(a0, b1, acc[0][1], 0, 0, 0);
                acc[1][0] = __builtin_amdgcn_mfma_f32_32x32x16_bf16(a1, b0, acc[1][0], 0, 0, 0);
                acc[1][1] = __builtin_amdgcn_mfma_f32_32x32x16_bf16(a1, b1, acc[1][1], 0, 0, 0);
            }
        }
    }

    // epilogue: 32x32 C/D layout (m74/m101): col=lane&31,
    // row = (r&3) + 8*(r>>2) + 4*(lane>>5)
    float* ob = out + (size_t)b * COUT * HW;
    #pragma unroll
    for (int m = 0; m < 2; ++m)
        #pragma unroll
        for (int n = 0; n < 2; ++n)
            #pragma unroll
            for (int r = 0; r < 16; ++r) {
                const int cout_l = 64 * wv + 32 * m + 4 * kg + (r & 3) + 8 * (r >> 2);
                const int p_ = p0 + 32 * n + ml;
                ob[(size_t)cout_l * HW + p_] = acc[m][n][r];
            }
}

// ---------------- R1 fallback (fp32 sparse direct) ----------------

constexpr int WSZ = CIN * 9;
constexpr int NIN = 54 * 54;

__global__ __launch_bounds__(256)
void sparse_conv3x3(const float* __restrict__ x,
                    const float* __restrict__ wgt,
                    float* __restrict__ out) {
    const int bc = blockIdx.x, cout = bc % COUT, b = bc / COUT;
    const int tid = threadIdx.x;
    __shared__ int2 s_ent[WSZ];
    __shared__ unsigned char s_kk[WSZ];
    __shared__ int s_cnt[257];
    const float* wc = wgt + (size_t)cout * WSZ;
    float mv[9]; int cnt = 0;
    #pragma unroll
    for (int i = 0; i < 9; ++i) { mv[i] = wc[tid * 9 + i]; if (mv[i] != 0.0f) cnt++; }
    s_cnt[tid] = cnt; __syncthreads();
    if (tid == 0) { int run = 0; for (int t = 0; t < 256; ++t) { int c = s_cnt[t]; s_cnt[t] = run; run += c; } s_cnt[256] = run; }
    __syncthreads();
    { int pos = s_cnt[tid];
      #pragma unroll
      for (int i = 0; i < 9; ++i) if (mv[i] != 0.0f) {
          const int kh = i / 3, kw = i - kh * 3;
          int2 e; e.x = (tid * HW + (kh - 1) * W + (kw - 1)) * 4; e.y = __float_as_int(mv[i]);
          s_ent[pos] = e; s_kk[pos] = (unsigned char)(kh | (kw << 4)); pos++; } }
    __syncthreads();
    const int nnz = s_cnt[256];
    const char* xb = (const char*)(x + (size_t)b * CIN * HW);
    float* ob = out + (size_t)bc * HW;
    for (int o = tid; o < HW; o += 256) {
        int h, w; bool interior = (o < NIN);
        if (interior) { h = 1 + o / 54; w = 1 + (o - (h - 1) * 54); }
        else { int o2 = o - NIN;
            if (o2 < 56) { h = 0; w = o2; } else if (o2 < 112) { h = 55; w = o2 - 56; }
            else if (o2 < 166) { h = 1 + (o2 - 112); w = 0; } else { h = 1 + (o2 - 166); w = 55; } }
        const char* pb = xb + (size_t)(h * W + w) * 4;
        float acc = 0.0f;
        if (interior) {
            #pragma unroll 4
            for (int e = 0; e < nnz; ++e) { const int2 en = s_ent[e];
                acc = fmaf(__int_as_float(en.y), *(const float*)(pb + en.x), acc); }
        } else {
            const int h1 = h - 1, w1 = w - 1;
            for (int e = 0; e < nnz; ++e) { const int2 en = s_ent[e]; const int kk = s_kk[e];
                const int hh = h1 + (kk & 15), ww = w1 + (kk >> 4);
                if ((unsigned)hh < (unsigned)H && (unsigned)ww < (unsigned)W)
                    acc = fmaf(__int_as_float(en.y), *(const float*)(pb + en.x), acc); } }
        ob[h * W + w] = acc;
    }
}

// ---------------- launch ----------------

extern "C" void kernel_launch(void* const* d_in, const int* in_sizes, int n_in,
                              void* d_out, int out_size, void* d_ws, size_t ws_size,
                              hipStream_t stream) {
    const float* x = (const float*)d_in[0];
    const float* w = (const float*)d_in[1];
    float* out = (float*)d_out;

    if (ws_size >= WS_NEEDED) {
        ushort* xp = (ushort*)d_ws;
        ushort* wbp = xp + XP_ELEMS;
        prep_xp<<<BB * HP, 256, 0, stream>>>(x, xp);
        prep_wb<<<(int)(WB_ELEMS / 256), 256, 0, stream>>>(w, wbp);
        conv_mfma<<<1568, 256, 0, stream>>>(xp, wbp, out);
    } else {
        sparse_conv3x3<<<BB * COUT, 256, 0, stream>>>(x, w, out);
    }
}

// Round 8
// 265.095 us; speedup vs baseline: 2.7174x; 1.1445x over previous
//
#include <hip/hip_runtime.h>

// 3x3 conv (sparse weights treated dense), NCHW/OIHW, stride1 pad1, fp32 I/O.
// B=32, CIN=COUT=256, H=W=56.
//
// R8: template-discipline K-loop: the ONLY VMEM ops in the loop are
// global_load_lds (A-tile staging, double-buffered) -> clean vmcnt stream.
//  - block = 256 cout x 64 pix, 4 waves, wave = 64c x 64p (m4 x n4, acc 64).
//  - K-step = (cin32-block, tap), 72 steps. A-tile 256x32 (20.5KB, [cout][40]
//    pad layout via chunk trick) staged per step; x-tile 4x58x[40] (18.5KB)
//    single-buffered, staged per cin-block, read with tap shifts.
//  - per tap: issue A(t+1) | ds_read 4a+4b | setprio MFMA x16 | vmcnt(0) | bar.
//  - LDS 60KB -> 2 blocks/CU; the 2 unsynchronized blocks give setprio
//    role-split (T5). Weights prebaked to wb2[(cb*9+tap)][cout][cin32].

typedef __attribute__((ext_vector_type(8))) short short8;
typedef __attribute__((ext_vector_type(4))) float f32x4;
typedef __attribute__((ext_vector_type(4))) int i32x4;

constexpr int BB = 32, CIN = 256, COUT = 256, H = 56, W = 56, HW = H * W;
constexpr int HP = 58, WP = 58;

constexpr size_t XP_ELEMS = (size_t)BB * HP * WP * CIN;
constexpr size_t WB_ELEMS = (size_t)COUT * 9 * CIN;
constexpr size_t WS_NEEDED = (XP_ELEMS + WB_ELEMS) * 2;

__device__ __forceinline__ ushort f2bf(float f) {
    unsigned x = __float_as_uint(f);
    unsigned r = (x + 0x7FFFu + ((x >> 16) & 1u)) >> 16;   // RNE
    return (ushort)r;
}

// ---------------- prep kernels ----------------

__global__ __launch_bounds__(256)
void prep_xp(const float* __restrict__ x, ushort* __restrict__ xp) {
    const int bi = blockIdx.x;            // b*58 + padded row i
    const int b = bi / HP, i = bi % HP;
    ushort* dst = xp + (size_t)bi * WP * CIN;
    const int tid = threadIdx.x;

    if (i == 0 || i == HP - 1) {
        i32x4 z = {0, 0, 0, 0};
        for (int k = tid; k < WP * CIN / 8; k += 256) ((i32x4*)dst)[k] = z;
        return;
    }

    __shared__ ushort t[W][CIN + 2];
    const int lane = tid & 63, wv = tid >> 6;
    if (lane < W) {
        const float* src = x + (size_t)b * CIN * HW + (size_t)(i - 1) * W + lane;
        for (int cin = wv; cin < CIN; cin += 4)
            t[lane][cin] = f2bf(src[(size_t)cin * HW]);
    }
    __syncthreads();
    for (int c = 0; c < WP; ++c)
        dst[c * CIN + tid] = (c == 0 || c == WP - 1) ? (ushort)0 : t[c - 1][tid];
}

// wb2 layout: [t = cb*9+tap][cout][ci], ci = cin%32, cb = cin/32. Slab = 8192 elems.
__global__ __launch_bounds__(256)
void prep_wb2(const float* __restrict__ w, ushort* __restrict__ wb2) {
    const int d = blockIdx.x * 256 + threadIdx.x;
    const int ci = d & 31;
    const int cout = (d >> 5) & 255;
    const int r = d >> 13;                // 0..71
    const int tap = r % 9, cb = r / 9;
    const int cin = cb * 32 + ci;
    wb2[d] = f2bf(w[((size_t)cout * CIN + cin) * 9 + tap]);
}

// ---------------- MFMA conv ----------------

#define SCHED_FENCE() __builtin_amdgcn_sched_barrier(0)

__device__ __forceinline__ void gload_lds16(const ushort* g, ushort* l) {
    __builtin_amdgcn_global_load_lds(
        (const __attribute__((address_space(1))) void*)g,
        (__attribute__((address_space(3))) void*)l, 16, 0, 0);
}

// chunk trick: chunk c = row*5 + piece; pieces 0..3 = 8 elems each (data),
// piece 4 = pad (dummy-loaded). Linear LDS dest = c*16B -> [row][40] layout.
constexpr int ACH = 1280;   // 256 couts * 5
constexpr int XCH = 1280;   // 232 slots * 5 = 1160 used, rest pad

__global__ __launch_bounds__(256, 2)
void conv_mfma(const ushort* __restrict__ xp, const ushort* __restrict__ wb2,
               float* __restrict__ out) {
    // XCD-aware swizzle: 1568 blocks = 8 * 196
    int bx = blockIdx.x;
    bx = (bx & 7) * 196 + (bx >> 3);

    const int b  = bx / 49;
    const int p0 = (bx % 49) * 64;         // 64-pix strip (spans <=2 out rows)
    const int r0 = p0 / 56;                // first padded input row

    const int tid  = threadIdx.x;
    const int wv   = tid >> 6;             // wave -> couts [64wv, 64wv+64)
    const int lane = tid & 63;
    const int ml   = lane & 15;
    const int g    = lane >> 4;

    __shared__ ushort As[2][ACH * 8];      // 2 x 20480B (A dbuf)
    __shared__ ushort xs[XCH * 8];         // 20480B (x, single buf)

    // B-frag LDS offsets: pixel p_ = p0 + 16nf + ml
    int boff[4];
    #pragma unroll
    for (int nf = 0; nf < 4; ++nf) {
        const int p_  = p0 + nf * 16 + ml;
        const int rr  = p_ / 56 - r0;      // 0 or 1
        const int col = p_ % 56;
        boff[nf] = (rr * 58 + col) * 40 + 8 * g;
    }
    // A-frag LDS offsets: cout = 64wv + 16mi + ml, k = 8g..8g+7
    int aoff[4];
    #pragma unroll
    for (int mi = 0; mi < 4; ++mi)
        aoff[mi] = (64 * wv + 16 * mi + ml) * 40 + 8 * g;

    // gload chunk source offsets (5 chunks per thread)
    int goffA[5], goffX[5];
    #pragma unroll
    for (int k = 0; k < 5; ++k) {
        const int c = 256 * k + tid;
        const int s = c / 5, pc = c - s * 5;
        goffX[k] = (c < 1160 && pc < 4) ? s * 256 + pc * 8 : 0;  // s = slot
        goffA[k] = (pc < 4) ? s * 32 + pc * 8 : 0;               // s = cout
    }
    const size_t xbase = ((size_t)b * HP + r0) * WP * CIN;

    f32x4 acc[4][4] = {};

    // prologue: x(cb0) + A(t=0) -> buf0
    #pragma unroll
    for (int k = 0; k < 5; ++k)
        gload_lds16(xp + xbase + goffX[k], &xs[(256 * k + 64 * wv) * 8]);
    #pragma unroll
    for (int k = 0; k < 5; ++k)
        gload_lds16(wb2 + goffA[k], &As[0][(256 * k + 64 * wv) * 8]);
    asm volatile("s_waitcnt vmcnt(0)" ::: "memory");
    __syncthreads();

    for (int cb = 0; cb < 8; ++cb) {
        #pragma unroll
        for (int tap = 0; tap < 9; ++tap) {
            const int t = cb * 9 + tap;
            const int cur = t & 1;
            const int tn = (t < 71) ? t + 1 : 0;      // dummy re-stage at end
            const ushort* asrc = wb2 + (size_t)tn * 8192;
            #pragma unroll
            for (int k = 0; k < 5; ++k)
                gload_lds16(asrc + goffA[k], &As[cur ^ 1][(256 * k + 64 * wv) * 8]);
            SCHED_FENCE();

            const int kh = tap / 3, kw = tap - kh * 3;
            const int toff = (kh * 58 + kw) * 40;
            const ushort* Ab = &As[cur][0];

            short8 av[4], bv[4];
            #pragma unroll
            for (int mi = 0; mi < 4; ++mi) av[mi] = *(const short8*)(Ab + aoff[mi]);
            #pragma unroll
            for (int nf = 0; nf < 4; ++nf) bv[nf] = *(const short8*)(xs + boff[nf] + toff);

            __builtin_amdgcn_s_setprio(1);
            #pragma unroll
            for (int mi = 0; mi < 4; ++mi)
                #pragma unroll
                for (int nf = 0; nf < 4; ++nf)
                    acc[mi][nf] = __builtin_amdgcn_mfma_f32_16x16x32_bf16(
                                      av[mi], bv[nf], acc[mi][nf], 0, 0, 0);
            __builtin_amdgcn_s_setprio(0);
            SCHED_FENCE();
            asm volatile("s_waitcnt vmcnt(0)" ::: "memory");  // A(t+1) landed (cover = tap body)
            SCHED_FENCE();
            __builtin_amdgcn_s_barrier();
        }
        if (cb < 7) {   // restage x for cb+1 (xs reads all done at tap8 barrier)
            #pragma unroll
            for (int k = 0; k < 5; ++k)
                gload_lds16(xp + xbase + (cb + 1) * 32 + goffX[k],
                            &xs[(256 * k + 64 * wv) * 8]);
            SCHED_FENCE();
            asm volatile("s_waitcnt vmcnt(0)" ::: "memory");
            SCHED_FENCE();
            __builtin_amdgcn_s_barrier();
        }
    }

    // epilogue: D[row=4g+r][col=ml] (verified R2-R7)
    float* ob = out + (size_t)b * COUT * HW;
    #pragma unroll
    for (int mi = 0; mi < 4; ++mi)
        #pragma unroll
        for (int nf = 0; nf < 4; ++nf)
            #pragma unroll
            for (int r = 0; r < 4; ++r) {
                const int cout_l = 64 * wv + 16 * mi + 4 * g + r;
                const int p_ = p0 + 16 * nf + ml;
                ob[(size_t)cout_l * HW + p_] = acc[mi][nf][r];
            }
}

// ---------------- R1 fallback (fp32 sparse direct) ----------------

constexpr int WSZ = CIN * 9;
constexpr int NIN = 54 * 54;

__global__ __launch_bounds__(256)
void sparse_conv3x3(const float* __restrict__ x,
                    const float* __restrict__ wgt,
                    float* __restrict__ out) {
    const int bc = blockIdx.x, cout = bc % COUT, b = bc / COUT;
    const int tid = threadIdx.x;
    __shared__ int2 s_ent[WSZ];
    __shared__ unsigned char s_kk[WSZ];
    __shared__ int s_cnt[257];
    const float* wc = wgt + (size_t)cout * WSZ;
    float mv[9]; int cnt = 0;
    #pragma unroll
    for (int i = 0; i < 9; ++i) { mv[i] = wc[tid * 9 + i]; if (mv[i] != 0.0f) cnt++; }
    s_cnt[tid] = cnt; __syncthreads();
    if (tid == 0) { int run = 0; for (int t = 0; t < 256; ++t) { int c = s_cnt[t]; s_cnt[t] = run; run += c; } s_cnt[256] = run; }
    __syncthreads();
    { int pos = s_cnt[tid];
      #pragma unroll
      for (int i = 0; i < 9; ++i) if (mv[i] != 0.0f) {
          const int kh = i / 3, kw = i - kh * 3;
          int2 e; e.x = (tid * HW + (kh - 1) * W + (kw - 1)) * 4; e.y = __float_as_int(mv[i]);
          s_ent[pos] = e; s_kk[pos] = (unsigned char)(kh | (kw << 4)); pos++; } }
    __syncthreads();
    const int nnz = s_cnt[256];
    const char* xb = (const char*)(x + (size_t)b * CIN * HW);
    float* ob = out + (size_t)bc * HW;
    for (int o = tid; o < HW; o += 256) {
        int h, w; bool interior = (o < NIN);
        if (interior) { h = 1 + o / 54; w = 1 + (o - (h - 1) * 54); }
        else { int o2 = o - NIN;
            if (o2 < 56) { h = 0; w = o2; } else if (o2 < 112) { h = 55; w = o2 - 56; }
            else if (o2 < 166) { h = 1 + (o2 - 112); w = 0; } else { h = 1 + (o2 - 166); w = 55; } }
        const char* pb = xb + (size_t)(h * W + w) * 4;
        float acc = 0.0f;
        if (interior) {
            #pragma unroll 4
            for (int e = 0; e < nnz; ++e) { const int2 en = s_ent[e];
                acc = fmaf(__int_as_float(en.y), *(const float*)(pb + en.x), acc); }
        } else {
            const int h1 = h - 1, w1 = w - 1;
            for (int e = 0; e < nnz; ++e) { const int2 en = s_ent[e]; const int kk = s_kk[e];
                const int hh = h1 + (kk & 15), ww = w1 + (kk >> 4);
                if ((unsigned)hh < (unsigned)H && (unsigned)ww < (unsigned)W)
                    acc = fmaf(__int_as_float(en.y), *(const float*)(pb + en.x), acc); } }
        ob[h * W + w] = acc;
    }
}

// ---------------- launch ----------------

extern "C" void kernel_launch(void* const* d_in, const int* in_sizes, int n_in,
                              void* d_out, int out_size, void* d_ws, size_t ws_size,
                              hipStream_t stream) {
    const float* x = (const float*)d_in[0];
    const float* w = (const float*)d_in[1];
    float* out = (float*)d_out;

    if (ws_size >= WS_NEEDED) {
        ushort* xp = (ushort*)d_ws;
        ushort* wbp = xp + XP_ELEMS;
        prep_xp<<<BB * HP, 256, 0, stream>>>(x, xp);
        prep_wb2<<<(int)(WB_ELEMS / 256), 256, 0, stream>>>(w, wbp);
        conv_mfma<<<1568, 256, 0, stream>>>(xp, wbp, out);
    } else {
        sparse_conv3x3<<<BB * COUT, 256, 0, stream>>>(x, w, out);
    }
}

// Round 9
// 161.957 us; speedup vs baseline: 4.4478x; 1.6368x over previous
//
#include <hip/hip_runtime.h>

// 3x3 conv (sparse weights treated dense), NCHW/OIHW, stride1 pad1, fp32 I/O.
// B=32, CIN=COUT=256, H=W=56.
//
// R9: m2n7 wave shape (R2's 104-reg footprint -> high TLP) + counted-vmcnt
// double-buffered staging (T3/T4), all VMEM via global_load_lds.
//  - block 256 cout x 112 pix, 8 waves, wave = 32c x 112p, acc[2][7]=56 AGPR.
//  - __launch_bounds__(512,4): reg cap 128 -> target 2 blocks/CU = 16 waves/CU
//    (4 waves/SIMD, 2x any prior round). LDS = 2x20KB A + 2x20KB X = 80KB.
//  - K-step t=(cb,tap), 72 steps: tap body = wait vmcnt(3|6) [never 0] ->
//    barrier -> ds_read 2A+7B -> 14 MFMA (setprio) -> barrier -> issue A(t+2)
//    [+X(cb+1) at tap7]. Writes always target a buffer all waves finished
//    reading (issue sits after the trailing barrier) -> race-free by structure.

typedef __attribute__((ext_vector_type(8))) short short8;
typedef __attribute__((ext_vector_type(4))) float f32x4;
typedef __attribute__((ext_vector_type(4))) int i32x4;

constexpr int BB = 32, CIN = 256, COUT = 256, H = 56, W = 56, HW = H * W;
constexpr int HP = 58, WP = 58;

constexpr size_t XP_ELEMS = (size_t)BB * HP * WP * CIN;
constexpr size_t WB_ELEMS = (size_t)COUT * 9 * CIN;
constexpr size_t WS_NEEDED = (XP_ELEMS + WB_ELEMS) * 2;

__device__ __forceinline__ ushort f2bf(float f) {
    unsigned x = __float_as_uint(f);
    unsigned r = (x + 0x7FFFu + ((x >> 16) & 1u)) >> 16;   // RNE
    return (ushort)r;
}

// ---------------- prep kernels ----------------

__global__ __launch_bounds__(256)
void prep_xp(const float* __restrict__ x, ushort* __restrict__ xp) {
    const int bi = blockIdx.x;            // b*58 + padded row i
    const int b = bi / HP, i = bi % HP;
    ushort* dst = xp + (size_t)bi * WP * CIN;
    const int tid = threadIdx.x;

    if (i == 0 || i == HP - 1) {
        i32x4 z = {0, 0, 0, 0};
        for (int k = tid; k < WP * CIN / 8; k += 256) ((i32x4*)dst)[k] = z;
        return;
    }

    __shared__ ushort t[W][CIN + 2];
    const int lane = tid & 63, wv = tid >> 6;
    if (lane < W) {
        const float* src = x + (size_t)b * CIN * HW + (size_t)(i - 1) * W + lane;
        for (int cin = wv; cin < CIN; cin += 4)
            t[lane][cin] = f2bf(src[(size_t)cin * HW]);
    }
    __syncthreads();
    for (int c = 0; c < WP; ++c)
        dst[c * CIN + tid] = (c == 0 || c == WP - 1) ? (ushort)0 : t[c - 1][tid];
}

// wb2 layout: [t = cb*9+tap][cout][ci], ci = cin%32, cb = cin/32. Slab = 8192 elems.
__global__ __launch_bounds__(256)
void prep_wb2(const float* __restrict__ w, ushort* __restrict__ wb2) {
    const int d = blockIdx.x * 256 + threadIdx.x;
    const int ci = d & 31;
    const int cout = (d >> 5) & 255;
    const int r = d >> 13;                // 0..71
    const int tap = r % 9, cb = r / 9;
    const int cin = cb * 32 + ci;
    wb2[d] = f2bf(w[((size_t)cout * CIN + cin) * 9 + tap]);
}

// ---------------- MFMA conv ----------------

#define SCHED_FENCE() __builtin_amdgcn_sched_barrier(0)
#define WAITV(N) asm volatile("s_waitcnt vmcnt(" #N ")" ::: "memory")

__device__ __forceinline__ void gload_lds16(const ushort* g, ushort* l) {
    __builtin_amdgcn_global_load_lds(
        (const __attribute__((address_space(1))) void*)g,
        (__attribute__((address_space(3))) void*)l, 16, 0, 0);
}

// chunk scheme: chunk c = row*5 + piece; pieces 0..3 = 8 elems data (64B/row),
// piece 4 = pad -> [row][40]-elem LDS layout from linear 16B chunks.
// A-tile: 256 couts -> 1280 chunks (20480B). X-tile: 232 slots -> 1160 chunks,
// buffer padded to 1280. 3 gload insts x 512 threads cover 1536 chunk ids;
// ids >= real go to a dump region (X pad tail, never read).

__global__ __launch_bounds__(512, 4)
void conv_mfma(const ushort* __restrict__ xp, const ushort* __restrict__ wb2,
               float* __restrict__ out) {
    // XCD-aware swizzle: 896 blocks = 8 * 112
    int bx = blockIdx.x;
    bx = (bx & 7) * 112 + (bx >> 3);

    const int b  = bx / 28;
    const int p0 = (bx % 28) * 112;        // 112-pix strip = 2 output rows
    const int r0 = p0 / 56;                // first padded input row

    const int tid  = threadIdx.x;
    const int wv   = tid >> 6;             // 0..7, wave -> couts [32wv, 32wv+32)
    const int lane = tid & 63;
    const int ml   = lane & 15;
    const int g    = lane >> 4;

    __shared__ ushort As[2][1280 * 8];     // 2 x 20480B
    __shared__ ushort Xs[2][1280 * 8];     // 2 x 20480B (tail 1160.. = pad/dump)
    ushort* dump = &Xs[0][1160 * 8];       // 64 chunks of never-read space

    // B-frag LDS offsets: pixel p_ = p0 + 16nf + ml
    int boff[7];
    #pragma unroll
    for (int nf = 0; nf < 7; ++nf) {
        const int p_  = p0 + nf * 16 + ml;
        const int hl  = (p_ >= p0 + 56) ? 1 : 0;
        const int col = p_ - 56 * (r0 + hl);
        boff[nf] = (hl * 58 + col) * 40 + 8 * g;
    }
    // A-frag LDS offsets: cout = 32wv + 16m + ml
    int aoff[2];
    #pragma unroll
    for (int m = 0; m < 2; ++m)
        aoff[m] = (32 * wv + 16 * m + ml) * 40 + 8 * g;

    // staging source offsets (3 chunk-insts per thread)
    int goffA[3], goffX[3];
    #pragma unroll
    for (int k = 0; k < 3; ++k) {
        const int c = 512 * k + tid;
        const int s = c / 5, pc = c - s * 5;
        goffA[k] = (c < 1280 && pc < 4) ? s * 32 + pc * 8 : 0;
        goffX[k] = (c < 1160 && pc < 4) ? s * 256 + pc * 8 : 0;
    }
    const size_t xbase = ((size_t)b * HP + r0) * WP * CIN;

    f32x4 acc[2][7] = {};

    // ---- staging helpers (wave-uniform dest; k==2 & wv>=4 -> dump) ----
    #define STAGE_A(T, BUF)                                                     \
        { const ushort* _s = wb2 + (size_t)(T) * 8192;                          \
          _Pragma("unroll")                                                     \
          for (int k = 0; k < 3; ++k) {                                         \
              ushort* _d = (k == 2 && wv >= 4) ? dump                           \
                           : &As[BUF][(512 * k + 64 * wv) * 8];                 \
              gload_lds16(_s + goffA[k], _d);                                   \
          } }
    #define STAGE_X(CB, BUF)                                                    \
        { const ushort* _s = xp + xbase + (CB) * 32;                            \
          _Pragma("unroll")                                                     \
          for (int k = 0; k < 3; ++k) {                                         \
              ushort* _d = (k == 2 && wv >= 4) ? dump                           \
                           : &Xs[BUF][(512 * k + 64 * wv) * 8];                 \
              gload_lds16(_s + goffX[k], _d);                                   \
          } }

    // prologue: A(0)->buf0, A(1)->buf1, X(0)->buf0; drain once; sync
    STAGE_A(0, 0);
    STAGE_A(1, 1);
    STAGE_X(0, 0);
    WAITV(0);
    __builtin_amdgcn_s_barrier();

    #pragma unroll
    for (int cb = 0; cb < 8; ++cb) {
        #pragma unroll
        for (int tap = 0; tap < 9; ++tap) {
            const int t = cb * 9 + tap;

            // ---- wait own contribution to As[t&1] (and Xs at tap0) landed ----
            if (t == 71)                            { WAITV(0); }
            else if ((tap == 7 || tap == 8) && cb < 7) { WAITV(6); }
            else                                    { WAITV(3); }
            SCHED_FENCE();
            __builtin_amdgcn_s_barrier();          // tile complete for all waves
            SCHED_FENCE();

            // ---- compute ----
            const ushort* Ab = &As[t & 1][0];
            const ushort* Xb = &Xs[cb & 1][0];
            const int kh = tap / 3, kw = tap - kh * 3;
            const int toff = (kh * 58 + kw) * 40;

            short8 av[2], bv[7];
            #pragma unroll
            for (int m = 0; m < 2; ++m) av[m] = *(const short8*)(Ab + aoff[m]);
            #pragma unroll
            for (int nf = 0; nf < 7; ++nf) bv[nf] = *(const short8*)(Xb + boff[nf] + toff);

            __builtin_amdgcn_s_setprio(1);
            #pragma unroll
            for (int m = 0; m < 2; ++m)
                #pragma unroll
                for (int nf = 0; nf < 7; ++nf)
                    acc[m][nf] = __builtin_amdgcn_mfma_f32_16x16x32_bf16(
                                     av[m], bv[nf], acc[m][nf], 0, 0, 0);
            __builtin_amdgcn_s_setprio(0);
            SCHED_FENCE();
            __builtin_amdgcn_s_barrier();          // all waves done reading
            SCHED_FENCE();

            // ---- tail: issue prefetches into just-freed buffers ----
            if (t < 70) STAGE_A(t + 2, t & 1);     // As[t&1] free after barrier2
            if (tap == 7 && cb < 7) STAGE_X(cb + 1, (cb + 1) & 1);
            SCHED_FENCE();
        }
    }

    // epilogue: D[row=4g+r][col=ml] (verified R2-R8)
    float* ob = out + (size_t)b * COUT * HW;
    #pragma unroll
    for (int m = 0; m < 2; ++m)
        #pragma unroll
        for (int nf = 0; nf < 7; ++nf)
            #pragma unroll
            for (int r = 0; r < 4; ++r) {
                const int cout_l = 32 * wv + 16 * m + 4 * g + r;
                const int p_ = p0 + 16 * nf + ml;
                ob[(size_t)cout_l * HW + p_] = acc[m][nf][r];
            }
    #undef STAGE_A
    #undef STAGE_X
}

// ---------------- R1 fallback (fp32 sparse direct) ----------------

constexpr int WSZ = CIN * 9;
constexpr int NIN = 54 * 54;

__global__ __launch_bounds__(256)
void sparse_conv3x3(const float* __restrict__ x,
                    const float* __restrict__ wgt,
                    float* __restrict__ out) {
    const int bc = blockIdx.x, cout = bc % COUT, b = bc / COUT;
    const int tid = threadIdx.x;
    __shared__ int2 s_ent[WSZ];
    __shared__ unsigned char s_kk[WSZ];
    __shared__ int s_cnt[257];
    const float* wc = wgt + (size_t)cout * WSZ;
    float mv[9]; int cnt = 0;
    #pragma unroll
    for (int i = 0; i < 9; ++i) { mv[i] = wc[tid * 9 + i]; if (mv[i] != 0.0f) cnt++; }
    s_cnt[tid] = cnt; __syncthreads();
    if (tid == 0) { int run = 0; for (int t = 0; t < 256; ++t) { int c = s_cnt[t]; s_cnt[t] = run; run += c; } s_cnt[256] = run; }
    __syncthreads();
    { int pos = s_cnt[tid];
      #pragma unroll
      for (int i = 0; i < 9; ++i) if (mv[i] != 0.0f) {
          const int kh = i / 3, kw = i - kh * 3;
          int2 e; e.x = (tid * HW + (kh - 1) * W + (kw - 1)) * 4; e.y = __float_as_int(mv[i]);
          s_ent[pos] = e; s_kk[pos] = (unsigned char)(kh | (kw << 4)); pos++; } }
    __syncthreads();
    const int nnz = s_cnt[256];
    const char* xb = (const char*)(x + (size_t)b * CIN * HW);
    float* ob = out + (size_t)bc * HW;
    for (int o = tid; o < HW; o += 256) {
        int h, w; bool interior = (o < NIN);
        if (interior) { h = 1 + o / 54; w = 1 + (o - (h - 1) * 54); }
        else { int o2 = o - NIN;
            if (o2 < 56) { h = 0; w = o2; } else if (o2 < 112) { h = 55; w = o2 - 56; }
            else if (o2 < 166) { h = 1 + (o2 - 112); w = 0; } else { h = 1 + (o2 - 166); w = 55; } }
        const char* pb = xb + (size_t)(h * W + w) * 4;
        float acc = 0.0f;
        if (interior) {
            #pragma unroll 4
            for (int e = 0; e < nnz; ++e) { const int2 en = s_ent[e];
                acc = fmaf(__int_as_float(en.y), *(const float*)(pb + en.x), acc); }
        } else {
            const int h1 = h - 1, w1 = w - 1;
            for (int e = 0; e < nnz; ++e) { const int2 en = s_ent[e]; const int kk = s_kk[e];
                const int hh = h1 + (kk & 15), ww = w1 + (kk >> 4);
                if ((unsigned)hh < (unsigned)H && (unsigned)ww < (unsigned)W)
                    acc = fmaf(__int_as_float(en.y), *(const float*)(pb + en.x), acc); } }
        ob[h * W + w] = acc;
    }
}

// ---------------- launch ----------------

extern "C" void kernel_launch(void* const* d_in, const int* in_sizes, int n_in,
                              void* d_out, int out_size, void* d_ws, size_t ws_size,
                              hipStream_t stream) {
    const float* x = (const float*)d_in[0];
    const float* w = (const float*)d_in[1];
    float* out = (float*)d_out;

    if (ws_size >= WS_NEEDED) {
        ushort* xp = (ushort*)d_ws;
        ushort* wbp = xp + XP_ELEMS;
        prep_xp<<<BB * HP, 256, 0, stream>>>(x, xp);
        prep_wb2<<<(int)(WB_ELEMS / 256), 256, 0, stream>>>(w, wbp);
        conv_mfma<<<896, 512, 0, stream>>>(xp, wbp, out);
    } else {
        sparse_conv3x3<<<BB * COUT, 256, 0, stream>>>(x, w, out);
    }
}

// Round 10
// 158.205 us; speedup vs baseline: 4.5533x; 1.0237x over previous
//
#include <hip/hip_runtime.h>

// 3x3 conv (sparse weights treated dense), NCHW/OIHW, stride1 pad1, fp32 I/O.
// B=32, CIN=COUT=256, H=W=56.
//
// R10 = R5's m4n7 wave shape (0.39 LDS-reads/MFMA) x R9's counted-vmcnt
// all-gload_lds double-buffered pipeline.
//  - block 256 thr / 4 waves, wave = 64 cout x 112 pix, acc[4][7] = 112 AGPR.
//  - A (per-tap 256x32 slab) + X (per-cb 4x58 rows) dbuf in LDS: 80KB exactly
//    -> 2 blocks/CU (two unsynced blocks/CU give setprio role-split).
//  - K-step t=(cb,tap): wait vmcnt(5) [10 at tap8 when X in flight; 0 only at
//    t=71] -> barrier -> ds_read 4A+7B -> setprio MFMA x28 -> barrier ->
//    issue A(t+2) [+X(cb+1) at tap7 tail]. Loads span >=2 taps of cover.

typedef __attribute__((ext_vector_type(8))) short short8;
typedef __attribute__((ext_vector_type(4))) float f32x4;
typedef __attribute__((ext_vector_type(4))) int i32x4;

constexpr int BB = 32, CIN = 256, COUT = 256, H = 56, W = 56, HW = H * W;
constexpr int HP = 58, WP = 58;

constexpr size_t XP_ELEMS = (size_t)BB * HP * WP * CIN;
constexpr size_t WB_ELEMS = (size_t)COUT * 9 * CIN;
constexpr size_t WS_NEEDED = (XP_ELEMS + WB_ELEMS) * 2;

__device__ __forceinline__ ushort f2bf(float f) {
    unsigned x = __float_as_uint(f);
    unsigned r = (x + 0x7FFFu + ((x >> 16) & 1u)) >> 16;   // RNE
    return (ushort)r;
}

// ---------------- prep kernels ----------------

__global__ __launch_bounds__(256)
void prep_xp(const float* __restrict__ x, ushort* __restrict__ xp) {
    const int bi = blockIdx.x;            // b*58 + padded row i
    const int b = bi / HP, i = bi % HP;
    ushort* dst = xp + (size_t)bi * WP * CIN;
    const int tid = threadIdx.x;

    if (i == 0 || i == HP - 1) {
        i32x4 z = {0, 0, 0, 0};
        for (int k = tid; k < WP * CIN / 8; k += 256) ((i32x4*)dst)[k] = z;
        return;
    }

    __shared__ ushort t[W][CIN + 2];
    const int lane = tid & 63, wv = tid >> 6;
    if (lane < W) {
        const float* src = x + (size_t)b * CIN * HW + (size_t)(i - 1) * W + lane;
        for (int cin = wv; cin < CIN; cin += 4)
            t[lane][cin] = f2bf(src[(size_t)cin * HW]);
    }
    __syncthreads();
    for (int c = 0; c < WP; ++c)
        dst[c * CIN + tid] = (c == 0 || c == WP - 1) ? (ushort)0 : t[c - 1][tid];
}

// wb2 layout: [t = cb*9+tap][cout][ci], ci = cin%32, cb = cin/32. Slab = 8192 elems.
__global__ __launch_bounds__(256)
void prep_wb2(const float* __restrict__ w, ushort* __restrict__ wb2) {
    const int d = blockIdx.x * 256 + threadIdx.x;
    const int ci = d & 31;
    const int cout = (d >> 5) & 255;
    const int r = d >> 13;                // 0..71
    const int tap = r % 9, cb = r / 9;
    const int cin = cb * 32 + ci;
    wb2[d] = f2bf(w[((size_t)cout * CIN + cin) * 9 + tap]);
}

// ---------------- MFMA conv ----------------

#define SCHED_FENCE() __builtin_amdgcn_sched_barrier(0)
#define WAITV(N) asm volatile("s_waitcnt vmcnt(" #N ")" ::: "memory")

__device__ __forceinline__ void gload_lds16(const ushort* g, ushort* l) {
    __builtin_amdgcn_global_load_lds(
        (const __attribute__((address_space(1))) void*)g,
        (__attribute__((address_space(3))) void*)l, 16, 0, 0);
}

// chunk scheme: chunk c = row*5 + piece; pieces 0..3 = 8 elems data (64B/row),
// piece 4 = pad (written with dummy data, never read) -> [row][40] layout.
// A-tile: 256 couts = 1280 chunks (20480B, exact). X-tile: 232 slots = 1160
// chunks used, buffer padded to 1280; chunk ids >= 1160 write garbage into
// the never-read tail.

__global__ __launch_bounds__(256, 2)
void conv_mfma(const ushort* __restrict__ xp, const ushort* __restrict__ wb2,
               float* __restrict__ out) {
    // XCD-aware swizzle: 896 blocks = 8 * 112
    int bx = blockIdx.x;
    bx = (bx & 7) * 112 + (bx >> 3);

    const int b  = bx / 28;
    const int p0 = (bx % 28) * 112;        // 112-pix strip = 2 output rows
    const int r0 = p0 / 56;                // first padded input row

    const int tid  = threadIdx.x;
    const int wv   = tid >> 6;             // 0..3, wave -> couts [64wv, 64wv+64)
    const int lane = tid & 63;
    const int ml   = lane & 15;
    const int g    = lane >> 4;

    __shared__ ushort As[2][1280 * 8];     // 2 x 20480B
    __shared__ ushort Xs[2][1280 * 8];     // 2 x 20480B (tail = pad, never read)

    // B-frag LDS offsets: pixel p_ = p0 + 16nf + ml
    int boff[7];
    #pragma unroll
    for (int nf = 0; nf < 7; ++nf) {
        const int p_  = p0 + nf * 16 + ml;
        const int hl  = (p_ >= p0 + 56) ? 1 : 0;
        const int col = p_ - 56 * (r0 + hl);
        boff[nf] = (hl * 58 + col) * 40 + 8 * g;
    }
    // A-frag LDS offsets: cout = 64wv + 16mi + ml
    int aoff[4];
    #pragma unroll
    for (int mi = 0; mi < 4; ++mi)
        aoff[mi] = (64 * wv + 16 * mi + ml) * 40 + 8 * g;

    // staging source offsets (5 chunk-insts per thread, 256 thr x 5 = 1280)
    int goffA[5], goffX[5];
    #pragma unroll
    for (int k = 0; k < 5; ++k) {
        const int c = 256 * k + tid;
        const int s = c / 5, pc = c - s * 5;
        goffA[k] = (pc < 4) ? s * 32 + pc * 8 : 0;               // s = cout
        goffX[k] = (c < 1160 && pc < 4) ? s * 256 + pc * 8 : 0;  // s = slot
    }
    const size_t xbase = ((size_t)b * HP + r0) * WP * CIN;

    f32x4 acc[4][7] = {};

    #define STAGE_A(T, BUF)                                                     \
        { const ushort* _s = wb2 + (size_t)(T) * 8192;                          \
          _Pragma("unroll")                                                     \
          for (int k = 0; k < 5; ++k)                                           \
              gload_lds16(_s + goffA[k], &As[BUF][(256 * k + 64 * wv) * 8]);    \
        }
    #define STAGE_X(CB, BUF)                                                    \
        { const ushort* _s = xp + xbase + (CB) * 32;                            \
          _Pragma("unroll")                                                     \
          for (int k = 0; k < 5; ++k)                                           \
              gload_lds16(_s + goffX[k], &Xs[BUF][(256 * k + 64 * wv) * 8]);    \
        }

    // prologue: A(0)->buf0, A(1)->buf1, X(0)->buf0; drain once; sync
    STAGE_A(0, 0);
    STAGE_A(1, 1);
    STAGE_X(0, 0);
    WAITV(0);
    __builtin_amdgcn_s_barrier();

    #pragma unroll
    for (int cb = 0; cb < 8; ++cb) {
        #pragma unroll
        for (int tap = 0; tap < 9; ++tap) {
            const int t = cb * 9 + tap;

            // ---- head: wait own contribution to the tiles read this tap ----
            if (t == 71)                      { WAITV(0); }
            else if (tap == 8 && cb < 7)      { WAITV(10); }  // A(t+1)+X in flight
            else                              { WAITV(5);  }  // A(t+1) in flight
            SCHED_FENCE();
            __builtin_amdgcn_s_barrier();     // tiles complete for all waves
            SCHED_FENCE();

            // ---- compute ----
            const ushort* Ab = &As[t & 1][0];
            const ushort* Xb = &Xs[cb & 1][0];
            const int kh = tap / 3, kw = tap - kh * 3;
            const int toff = (kh * 58 + kw) * 40;

            short8 av[4], bv[7];
            #pragma unroll
            for (int mi = 0; mi < 4; ++mi) av[mi] = *(const short8*)(Ab + aoff[mi]);
            #pragma unroll
            for (int nf = 0; nf < 7; ++nf) bv[nf] = *(const short8*)(Xb + boff[nf] + toff);

            __builtin_amdgcn_s_setprio(1);
            #pragma unroll
            for (int mi = 0; mi < 4; ++mi)
                #pragma unroll
                for (int nf = 0; nf < 7; ++nf)
                    acc[mi][nf] = __builtin_amdgcn_mfma_f32_16x16x32_bf16(
                                      av[mi], bv[nf], acc[mi][nf], 0, 0, 0);
            __builtin_amdgcn_s_setprio(0);
            SCHED_FENCE();
            __builtin_amdgcn_s_barrier();     // all waves done reading
            SCHED_FENCE();

            // ---- tail: issue prefetches into just-freed buffers ----
            if (t < 70) STAGE_A(t + 2, t & 1);
            if (tap == 7 && cb < 7) STAGE_X(cb + 1, (cb + 1) & 1);
            SCHED_FENCE();
        }
    }

    // epilogue: D[row=4g+r][col=ml] (verified R2-R9)
    float* ob = out + (size_t)b * COUT * HW;
    #pragma unroll
    for (int mi = 0; mi < 4; ++mi)
        #pragma unroll
        for (int nf = 0; nf < 7; ++nf)
            #pragma unroll
            for (int r = 0; r < 4; ++r) {
                const int cout_l = 64 * wv + 16 * mi + 4 * g + r;
                const int p_ = p0 + 16 * nf + ml;
                ob[(size_t)cout_l * HW + p_] = acc[mi][nf][r];
            }
    #undef STAGE_A
    #undef STAGE_X
}

// ---------------- R1 fallback (fp32 sparse direct) ----------------

constexpr int WSZ = CIN * 9;
constexpr int NIN = 54 * 54;

__global__ __launch_bounds__(256)
void sparse_conv3x3(const float* __restrict__ x,
                    const float* __restrict__ wgt,
                    float* __restrict__ out) {
    const int bc = blockIdx.x, cout = bc % COUT, b = bc / COUT;
    const int tid = threadIdx.x;
    __shared__ int2 s_ent[WSZ];
    __shared__ unsigned char s_kk[WSZ];
    __shared__ int s_cnt[257];
    const float* wc = wgt + (size_t)cout * WSZ;
    float mv[9]; int cnt = 0;
    #pragma unroll
    for (int i = 0; i < 9; ++i) { mv[i] = wc[tid * 9 + i]; if (mv[i] != 0.0f) cnt++; }
    s_cnt[tid] = cnt; __syncthreads();
    if (tid == 0) { int run = 0; for (int t = 0; t < 256; ++t) { int c = s_cnt[t]; s_cnt[t] = run; run += c; } s_cnt[256] = run; }
    __syncthreads();
    { int pos = s_cnt[tid];
      #pragma unroll
      for (int i = 0; i < 9; ++i) if (mv[i] != 0.0f) {
          const int kh = i / 3, kw = i - kh * 3;
          int2 e; e.x = (tid * HW + (kh - 1) * W + (kw - 1)) * 4; e.y = __float_as_int(mv[i]);
          s_ent[pos] = e; s_kk[pos] = (unsigned char)(kh | (kw << 4)); pos++; } }
    __syncthreads();
    const int nnz = s_cnt[256];
    const char* xb = (const char*)(x + (size_t)b * CIN * HW);
    float* ob = out + (size_t)bc * HW;
    for (int o = tid; o < HW; o += 256) {
        int h, w; bool interior = (o < NIN);
        if (interior) { h = 1 + o / 54; w = 1 + (o - (h - 1) * 54); }
        else { int o2 = o - NIN;
            if (o2 < 56) { h = 0; w = o2; } else if (o2 < 112) { h = 55; w = o2 - 56; }
            else if (o2 < 166) { h = 1 + (o2 - 112); w = 0; } else { h = 1 + (o2 - 166); w = 55; } }
        const char* pb = xb + (size_t)(h * W + w) * 4;
        float acc = 0.0f;
        if (interior) {
            #pragma unroll 4
            for (int e = 0; e < nnz; ++e) { const int2 en = s_ent[e];
                acc = fmaf(__int_as_float(en.y), *(const float*)(pb + en.x), acc); }
        } else {
            const int h1 = h - 1, w1 = w - 1;
            for (int e = 0; e < nnz; ++e) { const int2 en = s_ent[e]; const int kk = s_kk[e];
                const int hh = h1 + (kk & 15), ww = w1 + (kk >> 4);
                if ((unsigned)hh < (unsigned)H && (unsigned)ww < (unsigned)W)
                    acc = fmaf(__int_as_float(en.y), *(const float*)(pb + en.x), acc); } }
        ob[h * W + w] = acc;
    }
}

// ---------------- launch ----------------

extern "C" void kernel_launch(void* const* d_in, const int* in_sizes, int n_in,
                              void* d_out, int out_size, void* d_ws, size_t ws_size,
                              hipStream_t stream) {
    const float* x = (const float*)d_in[0];
    const float* w = (const float*)d_in[1];
    float* out = (float*)d_out;

    if (ws_size >= WS_NEEDED) {
        ushort* xp = (ushort*)d_ws;
        ushort* wbp = xp + XP_ELEMS;
        prep_xp<<<BB * HP, 256, 0, stream>>>(x, xp);
        prep_wb2<<<(int)(WB_ELEMS / 256), 256, 0, stream>>>(w, wbp);
        conv_mfma<<<896, 256, 0, stream>>>(xp, wbp, out);
    } else {
        sparse_conv3x3<<<BB * COUT, 256, 0, stream>>>(x, w, out);
    }
}